// Round 19
// baseline (55.192 us; speedup 1.0000x reference)
//
#include <hip/hip_runtime.h>
#include <hip/hip_cooperative_groups.h>
#include <math.h>

namespace cg = cooperative_groups;

#define BATCH 8
#define LEN   2048
#define FEAT  8
#define MROWS 64                      // 2 row-groups x 32 rows
#define THREADS 1024                  // 16 waves: rg = w>>3, jo = w&7
#define JO    (LEN / 8)               // 256 targets per j-octant
#define NCHUNK (JO / 16)              // 16 chunks x 2 MFMAs per wave
#define NBLK  (BATCH * (LEN / MROWS)) // 256 blocks = 1/CU (co-resident)
#define LOG2E 1.4426950408889634f
#define LN2   0.6931471805599453f
#define P2S   (2.0f * LOG2E)          // pred pre-scale

typedef _Float16 f16x8 __attribute__((ext_vector_type(8)));
typedef float    f32x4 __attribute__((ext_vector_type(4)));

__device__ __forceinline__ float exp2_hw(float x) {
    float d; asm("v_exp_f32 %0, %1" : "=v"(d) : "v"(x)); return d;
}
__device__ __forceinline__ float log2_hw(float x) {
    float d; asm("v_log_f32 %0, %1" : "=v"(d) : "v"(x)); return d;
}

// Round-19: ONE-NODE graph via cooperative launch. Measured ledger:
//   k1+gap = 7.39us (R17 calibration), k2+fixed = 6.94us (trivial kernel!),
//   atomic-tail fusion = +6us even at 256 relaxed RMWs (R18 vs R14, equal
//   node count -> tail isolated).
// So: kill BOTH the second node and the atomic protocol with grid.sync():
// plain per-block partial stores (no RMW, no init -> no memset node),
// grid-wide barrier, block 0 reduces 256 floats in fixed order (bitwise
// deterministic). 256 blocks x 1024 threads = exactly 1 block/CU ->
// co-residency guaranteed for cooperative launch.
// Compute body is byte-identical to round-14 (best k1): MFMA data only in
// lane-group 0, S = 2*log2e*u.tau, x = S + mt2, row = log2(sum exp2 x) - qp.
__global__ __launch_bounds__(THREADS, 4) void dtw_coop(
    const float* __restrict__ pred, const float* __restrict__ target,
    float* __restrict__ partial, float* __restrict__ out)
{
    __shared__ f16x8 s_t16[LEN];        // 32 KB fp16 tau rows
    __shared__ float s_mt2[LEN];        // 8 KB  -log2e*||tau||^2
    __shared__ float s_red[MROWS * 8];  // 2 KB  per-(row, jo) partials
    __shared__ float s_qp[MROWS];       // 256 B per-row log2e*||u||^2

    const int tid = threadIdx.x;
    const int b   = blockIdx.x / (LEN / MROWS);
    const int rs  = blockIdx.x % (LEN / MROWS);
    const int w   = tid >> 6;
    const int rg  = w >> 3;            // row-group 0..1
    const int jo  = w & 7;             // j-octant 0..7
    const int ln  = tid & 63;
    const int col = ln & 15;
    const int g   = ln >> 4;           // lane-group
    const int i0  = rs * MROWS + rg * 32;

    // ---- stage all 2048 target rows of batch b (2 rows per thread) ----
    const float4* t4 = (const float4*)(target + (size_t)b * LEN * FEAT);
    #pragma unroll
    for (int u = 0; u < LEN / THREADS; ++u) {
        const int jj = u * THREADS + tid;
        float4 ta = t4[(size_t)jj * 2];
        float4 tb = t4[(size_t)jj * 2 + 1];
        f16x8 h;
        h[0] = (_Float16)ta.x; h[1] = (_Float16)ta.y;
        h[2] = (_Float16)ta.z; h[3] = (_Float16)ta.w;
        h[4] = (_Float16)tb.x; h[5] = (_Float16)tb.y;
        h[6] = (_Float16)tb.z; h[7] = (_Float16)tb.w;
        float t2 = 0.f;
        #pragma unroll
        for (int e = 0; e < 8; ++e) { float f = (float)h[e]; t2 += f * f; }
        s_t16[jj] = h;
        s_mt2[jj] = -LOG2E * t2;
    }

    // ---- two A-frags: pred rows i0+col and i0+16+col (fp16, x 2*log2e) ----
    f16x8 afrag0, afrag1;
    #pragma unroll
    for (int e = 0; e < 8; ++e) { afrag0[e] = (_Float16)0.f;
                                  afrag1[e] = (_Float16)0.f; }
    {
        const float* pb = pred + ((size_t)b * LEN + i0 + col) * FEAT;
        const float4* pA = (const float4*)pb;
        const float4* pB = (const float4*)(pb + 16 * FEAT);
        float4 a0 = pA[0], c0 = pA[1], a1 = pB[0], c1 = pB[1];
        float f0[8] = {a0.x, a0.y, a0.z, a0.w, c0.x, c0.y, c0.z, c0.w};
        float f1[8] = {a1.x, a1.y, a1.z, a1.w, c1.x, c1.y, c1.z, c1.w};
        f16x8 r0, r1;
        float e0 = 0.f, e1 = 0.f;
        #pragma unroll
        for (int e = 0; e < 8; ++e) {
            r0[e] = (_Float16)(P2S * f0[e]);
            r1[e] = (_Float16)(P2S * f1[e]);
            float x0 = (float)r0[e], x1 = (float)r1[e];
            e0 += x0 * x0; e1 += x1 * x1;
        }
        if (g == 0) { afrag0 = r0; afrag1 = r1; }   // data only in group 0
        if (jo == 0 && g == 0) {
            s_qp[rg * 32 + col]      = e0 * (0.25f / LOG2E);
            s_qp[rg * 32 + 16 + col] = e1 * (0.25f / LOG2E);
        }
    }

    __syncthreads();   // staging + s_qp visible

    // ---- j-loop: 16 chunks, 1 b128 + 1 b32 (broadcast) -> 2 MFMAs ----
    const int jbase = jo * JO;
    f32x4 acc0 = {0.f, 0.f, 0.f, 0.f};
    f32x4 acc1 = {0.f, 0.f, 0.f, 0.f};
    const f32x4 Z = {0.f, 0.f, 0.f, 0.f};
    #pragma unroll
    for (int ch = 0; ch < NCHUNK; ++ch) {
        const int j0 = jbase + ch * 16;
        f16x8 bfrag = s_t16[j0 + col];     // all lanes: broadcast read
        float mt2c  = s_mt2[j0 + col];
        f32x4 S0 = __builtin_amdgcn_mfma_f32_16x16x32_f16(
            afrag0, bfrag, Z, 0, 0, 0);    // S = 2*log2e*u.tau
        f32x4 S1 = __builtin_amdgcn_mfma_f32_16x16x32_f16(
            afrag1, bfrag, Z, 0, 0, 0);
        #pragma unroll
        for (int r = 0; r < 4; ++r) {
            acc0[r] += exp2_hw(S0[r] + mt2c);   // = 2^qp0 * exp(-d~)
            acc1[r] += exp2_hw(S1[r] + mt2c);
        }
    }

    // ---- sum each row across its 16-lane col group ----
    #pragma unroll
    for (int m = 1; m < 16; m <<= 1) {
        #pragma unroll
        for (int r = 0; r < 4; ++r) {
            acc0[r] += __shfl_xor(acc0[r], m);
            acc1[r] += __shfl_xor(acc1[r], m);
        }
    }
    if (col == 0) {
        #pragma unroll
        for (int r = 0; r < 4; ++r) {
            s_red[(rg * 32 + g * 4 + r) * 8 + jo]      = acc0[r];
            s_red[(rg * 32 + 16 + g * 4 + r) * 8 + jo] = acc1[r];
        }
    }
    __syncthreads();

    // ---- per-row soft-min (subtract qp exactly), per-block partial ----
    if (tid < MROWS) {
        float s = 0.f;
        #pragma unroll
        for (int q = 0; q < 8; ++q) s += s_red[tid * 8 + q];
        float v = log2_hw(s) - s_qp[tid];   // log2(sum_j exp(-d~))
        v += __shfl_xor(v, 1);
        v += __shfl_xor(v, 2);
        v += __shfl_xor(v, 4);
        v += __shfl_xor(v, 8);
        v += __shfl_xor(v, 16);
        v += __shfl_xor(v, 32);
        if (tid == 0) {
            partial[blockIdx.x] = -LN2 * v;  // plain store (no RMW)
            __threadfence();                 // wave-0 only: 1 release/block
        }
    }

    // ---- grid-wide barrier, then block 0 reduces in fixed order ----
    cg::this_grid().sync();
    if (blockIdx.x == 0 && tid < NBLK) {     // waves 0-3
        float v = partial[tid];
        v += __shfl_xor(v, 1);
        v += __shfl_xor(v, 2);
        v += __shfl_xor(v, 4);
        v += __shfl_xor(v, 8);
        v += __shfl_xor(v, 16);
        v += __shfl_xor(v, 32);
        if ((tid & 63) == 0) s_qp[tid >> 6] = v;   // reuse s_qp
        __syncthreads();
        if (tid == 0)
            out[0] = (s_qp[0] + s_qp[1] + s_qp[2] + s_qp[3])
                   * (1.0f / (BATCH * LEN));
    }
}

extern "C" void kernel_launch(void* const* d_in, const int* in_sizes, int n_in,
                              void* d_out, int out_size, void* d_ws, size_t ws_size,
                              hipStream_t stream) {
    const float* pred   = (const float*)d_in[0];
    const float* target = (const float*)d_in[1];
    float* out     = (float*)d_out;
    float* partial = (float*)d_ws;

    void* args[] = { (void*)&pred, (void*)&target,
                     (void*)&partial, (void*)&out };
    hipLaunchCooperativeKernel((const void*)dtw_coop,
                               dim3(NBLK), dim3(THREADS), args, 0, stream);
}

// Round 20
// 14.107 us; speedup vs baseline: 3.9122x; 3.9122x over previous
//
#include <hip/hip_runtime.h>
#include <math.h>

#define BATCH 8
#define LEN   2048
#define FEAT  8
#define MROWS 64                      // 2 row-groups x 32 rows
#define THREADS 1024                  // 16 waves: rg = w>>3, jo = w&7
#define JO    (LEN / 8)               // 256 targets per j-octant
#define NCHUNK (JO / 16)              // 16 chunks x 2 MFMAs per wave
#define NBLK  (BATCH * (LEN / MROWS)) // 256 blocks = 1/CU
#define LOG2E 1.4426950408889634f
#define LN2   0.6931471805599453f
#define P2S   (2.0f * LOG2E)          // pred pre-scale

typedef _Float16 f16x8 __attribute__((ext_vector_type(8)));
typedef float    f32x4 __attribute__((ext_vector_type(4)));

__device__ __forceinline__ float exp2_hw(float x) {
    float d; asm("v_exp_f32 %0, %1" : "=v"(d) : "v"(x)); return d;
}
__device__ __forceinline__ float log2_hw(float x) {
    float d; asm("v_log_f32 %0, %1" : "=v"(d) : "v"(x)); return d;
}

// Round-20: RESTORATION of the measured optimum (round-14, 14.33us).
// Structural search is closed by measurement:
//   two-kernel 14.33 < fused+256-RMW 20.24 < 1024-RMW tails 34-41
//   < cooperative grid.sync 55.2.
// Ledger: k1+gap = 7.39us (R17 double-launch calibration), fixed+k2 = 6.94us.
// k1 (~6us) resisted occupancy x2, staging overlap, and two LDS-instr
// halvings (all within +-1us) -- the remaining time is graph/boundary
// overhead, not kernel compute. This file is the R14 kernel byte-for-byte.
//
// Math (HW-verified class): MFMA 16x16x32_f16 with data ONLY in lane-group 0
// (zeros elsewhere); A = fp16(2*log2e*p), B = tau = fp16(t);
// S = 2*log2e*u.tau (f32-exact products); x = S + mt2, mt2 = -log2e*||tau||^2;
// row value = log2(sum_j exp2(x)) - qp = log2(sum_j exp(-d~)),
// d~ = ||u - tau||^2 >= 0, qp = log2e*||u||^2 applied once post-reduction.
template <bool ATOMIC>
__global__ __launch_bounds__(THREADS, 4) void dtw_mfma(
    const float* __restrict__ pred, const float* __restrict__ target,
    float* __restrict__ partial_or_out)
{
    __shared__ f16x8 s_t16[LEN];        // 32 KB fp16 tau rows
    __shared__ float s_mt2[LEN];        // 8 KB  -log2e*||tau||^2
    __shared__ float s_red[MROWS * 8];  // 2 KB  per-(row, jo) partials
    __shared__ float s_qp[MROWS];       // 256 B per-row log2e*||u||^2

    const int tid = threadIdx.x;
    const int b   = blockIdx.x / (LEN / MROWS);
    const int rs  = blockIdx.x % (LEN / MROWS);
    const int w   = tid >> 6;
    const int rg  = w >> 3;            // row-group 0..1
    const int jo  = w & 7;             // j-octant 0..7
    const int ln  = tid & 63;
    const int col = ln & 15;
    const int g   = ln >> 4;           // lane-group
    const int i0  = rs * MROWS + rg * 32;

    // ---- stage all 2048 target rows of batch b (2 rows per thread) ----
    const float4* t4 = (const float4*)(target + (size_t)b * LEN * FEAT);
    #pragma unroll
    for (int u = 0; u < LEN / THREADS; ++u) {
        const int jj = u * THREADS + tid;
        float4 ta = t4[(size_t)jj * 2];
        float4 tb = t4[(size_t)jj * 2 + 1];
        f16x8 h;
        h[0] = (_Float16)ta.x; h[1] = (_Float16)ta.y;
        h[2] = (_Float16)ta.z; h[3] = (_Float16)ta.w;
        h[4] = (_Float16)tb.x; h[5] = (_Float16)tb.y;
        h[6] = (_Float16)tb.z; h[7] = (_Float16)tb.w;
        float t2 = 0.f;
        #pragma unroll
        for (int e = 0; e < 8; ++e) { float f = (float)h[e]; t2 += f * f; }
        s_t16[jj] = h;
        s_mt2[jj] = -LOG2E * t2;
    }

    // ---- two A-frags: pred rows i0+col and i0+16+col (fp16, x 2*log2e) ----
    f16x8 afrag0, afrag1;
    #pragma unroll
    for (int e = 0; e < 8; ++e) { afrag0[e] = (_Float16)0.f;
                                  afrag1[e] = (_Float16)0.f; }
    float qp0 = 0.f, qp1 = 0.f;
    {
        const float* pb = pred + ((size_t)b * LEN + i0 + col) * FEAT;
        const float4* pA = (const float4*)pb;
        const float4* pB = (const float4*)(pb + 16 * FEAT);
        float4 a0 = pA[0], c0 = pA[1], a1 = pB[0], c1 = pB[1];
        float f0[8] = {a0.x, a0.y, a0.z, a0.w, c0.x, c0.y, c0.z, c0.w};
        float f1[8] = {a1.x, a1.y, a1.z, a1.w, c1.x, c1.y, c1.z, c1.w};
        f16x8 r0, r1;
        float e0 = 0.f, e1 = 0.f;
        #pragma unroll
        for (int e = 0; e < 8; ++e) {
            r0[e] = (_Float16)(P2S * f0[e]);
            r1[e] = (_Float16)(P2S * f1[e]);
            float x0 = (float)r0[e], x1 = (float)r1[e];
            e0 += x0 * x0; e1 += x1 * x1;
        }
        qp0 = e0 * (0.25f / LOG2E);        // log2e * ||u0||^2
        qp1 = e1 * (0.25f / LOG2E);
        if (g == 0) { afrag0 = r0; afrag1 = r1; }   // data only in group 0
        if (jo == 0 && g == 0) {
            s_qp[rg * 32 + col]      = qp0;
            s_qp[rg * 32 + 16 + col] = qp1;
        }
    }

    __syncthreads();   // staging + s_qp visible

    // ---- j-loop: 16 chunks, 1 b128 + 1 b32 (broadcast) -> 2 MFMAs ----
    const int jbase = jo * JO;
    f32x4 acc0 = {0.f, 0.f, 0.f, 0.f};
    f32x4 acc1 = {0.f, 0.f, 0.f, 0.f};
    const f32x4 Z = {0.f, 0.f, 0.f, 0.f};
    #pragma unroll
    for (int ch = 0; ch < NCHUNK; ++ch) {
        const int j0 = jbase + ch * 16;
        f16x8 bfrag = s_t16[j0 + col];     // all lanes: broadcast read
        float mt2c  = s_mt2[j0 + col];
        f32x4 S0 = __builtin_amdgcn_mfma_f32_16x16x32_f16(
            afrag0, bfrag, Z, 0, 0, 0);    // S = 2*log2e*u.tau
        f32x4 S1 = __builtin_amdgcn_mfma_f32_16x16x32_f16(
            afrag1, bfrag, Z, 0, 0, 0);
        #pragma unroll
        for (int r = 0; r < 4; ++r) {
            acc0[r] += exp2_hw(S0[r] + mt2c);   // = 2^qp0 * exp(-d~)
            acc1[r] += exp2_hw(S1[r] + mt2c);
        }
    }

    // ---- sum each row across its 16-lane col group ----
    #pragma unroll
    for (int m = 1; m < 16; m <<= 1) {
        #pragma unroll
        for (int r = 0; r < 4; ++r) {
            acc0[r] += __shfl_xor(acc0[r], m);
            acc1[r] += __shfl_xor(acc1[r], m);
        }
    }
    if (col == 0) {
        #pragma unroll
        for (int r = 0; r < 4; ++r) {
            s_red[(rg * 32 + g * 4 + r) * 8 + jo]      = acc0[r];
            s_red[(rg * 32 + 16 + g * 4 + r) * 8 + jo] = acc1[r];
        }
    }
    __syncthreads();

    // ---- per-row soft-min (subtract qp exactly), block total ----
    if (tid < MROWS) {
        float s = 0.f;
        #pragma unroll
        for (int q = 0; q < 8; ++q) s += s_red[tid * 8 + q];
        float v = log2_hw(s) - s_qp[tid];   // log2(sum_j exp(-d~))
        v += __shfl_xor(v, 1);
        v += __shfl_xor(v, 2);
        v += __shfl_xor(v, 4);
        v += __shfl_xor(v, 8);
        v += __shfl_xor(v, 16);
        v += __shfl_xor(v, 32);
        if (tid == 0) {
            float tot = -LN2 * v;           // -gamma * ln-sum over 64 rows
            if (ATOMIC) {
                atomicAdd(partial_or_out, tot * (1.0f / (BATCH * LEN)));
            } else {
                partial_or_out[blockIdx.x] = tot;
            }
        }
    }
}

__global__ __launch_bounds__(256) void dtw_reduce(
    const float* __restrict__ partial, float* __restrict__ out)
{
    __shared__ float s_w[4];
    const int tid = threadIdx.x;
    float v = partial[tid];               // NBLK = 256
    v += __shfl_xor(v, 1);
    v += __shfl_xor(v, 2);
    v += __shfl_xor(v, 4);
    v += __shfl_xor(v, 8);
    v += __shfl_xor(v, 16);
    v += __shfl_xor(v, 32);
    if ((tid & 63) == 0) s_w[tid >> 6] = v;
    __syncthreads();
    if (tid == 0)
        out[0] = (s_w[0] + s_w[1] + s_w[2] + s_w[3]) * (1.0f / (BATCH * LEN));
}

extern "C" void kernel_launch(void* const* d_in, const int* in_sizes, int n_in,
                              void* d_out, int out_size, void* d_ws, size_t ws_size,
                              hipStream_t stream) {
    const float* pred   = (const float*)d_in[0];
    const float* target = (const float*)d_in[1];
    float* out = (float*)d_out;

    if (ws_size >= NBLK * sizeof(float)) {
        float* partial = (float*)d_ws;
        dtw_mfma<false><<<NBLK, THREADS, 0, stream>>>(pred, target, partial);
        dtw_reduce<<<1, 256, 0, stream>>>(partial, out);
    } else {
        hipMemsetAsync(d_out, 0, sizeof(float), stream);
        dtw_mfma<true><<<NBLK, THREADS, 0, stream>>>(pred, target, out);
    }
}